// Round 13
// baseline (238.851 us; speedup 1.0000x reference)
//
#include <hip/hip_runtime.h>
#include <float.h>
#include <math.h>

#define LL 32
#define BB 128
#define FF 4096
#define EE 512
#define HH 512
#define NLAYER 2
#define KK 20
#define NCH 32

typedef float f4 __attribute__((ext_vector_type(4)));
typedef short bf16x8 __attribute__((ext_vector_type(8)));
typedef float f32x4 __attribute__((ext_vector_type(4)));

__device__ inline unsigned short bf16rne(float x) {
    unsigned u = __float_as_uint(x);
    u += 0x7fff + ((u >> 16) & 1);
    return (unsigned short)(u >> 16);
}

// key==0 unreachable: requires raw float bits 0xFFFFFFFF (negative NaN), never produced.
__device__ inline unsigned long long packkey(float v, int fidx) {
    unsigned u = __float_as_uint(v);
    u ^= ((int)u >> 31) | 0x80000000u;
    return ((unsigned long long)u << 32) | (unsigned)(FF - 1 - fidx);
}

__device__ inline bf16x8 cvt8(f4 a, f4 b) {
    bf16x8 r;
    r[0] = (short)bf16rne(a.x); r[1] = (short)bf16rne(a.y);
    r[2] = (short)bf16rne(a.z); r[3] = (short)bf16rne(a.w);
    r[4] = (short)bf16rne(b.x); r[5] = (short)bf16rne(b.y);
    r[6] = (short)bf16rne(b.z); r[7] = (short)bf16rne(b.w);
    return r;
}

// ---------------- K1: q (0..255) + W->bf16 (256..767) + cand zero (768..783) ----------------
__global__ __launch_bounds__(256) void prep_kernel(const int* __restrict__ tok,
                                                   const float* __restrict__ emb,
                                                   float* __restrict__ q,
                                                   const float* __restrict__ Aw,
                                                   const float* __restrict__ Cw,
                                                   unsigned short* __restrict__ Wbf,
                                                   unsigned long long* __restrict__ cand) {
    int bid = blockIdx.x;
    if (bid < 256) {
        int b = bid >> 1, eh = bid & 1;
        __shared__ int ts[LL];
        if (threadIdx.x < LL) ts[threadIdx.x] = tok[threadIdx.x * BB + b];
        __syncthreads();
        int e = eh * 256 + threadIdx.x;
        float acc = 0.f;
        #pragma unroll
        for (int l = 0; l < LL; ++l) acc += emb[(long)ts[l] * EE + e];
        q[b * EE + e] = acc * (1.0f / LL);
    } else if (bid < 768) {
        int cid = bid - 256;
        int matY = cid >> 8;
        int blkX = cid & 255;
        const float* W = matY ? Cw : Aw;
        unsigned short* dst = Wbf + (size_t)matY * HH * EE;
        int i = (blkX * 256 + threadIdx.x) * 4;
        float4 v = *(const float4*)(W + i);
        ushort4 o;
        o.x = bf16rne(v.x); o.y = bf16rne(v.y); o.z = bf16rne(v.z); o.w = bf16rne(v.w);
        *(ushort4*)(dst + i) = o;
    } else {
        int idx = (bid - 768) * 256 + threadIdx.x;      // 0..4095
        unsigned long long* p = cand + (size_t)idx * KK;
        #pragma unroll
        for (int i = 0; i < KK; ++i) p[i] = 0ull;
    }
}

// ---------------- K2: mega — scoring producers (0..4095) + fused tails (4096..4351) ----------------
__global__ __launch_bounds__(256) void mega_kernel(const float* __restrict__ q,
                                                   const float* __restrict__ fact,
                                                   const float* __restrict__ hin,
                                                   const float* __restrict__ cin,
                                                   const unsigned short* __restrict__ Wbf,
                                                   const float* __restrict__ Ab,
                                                   const float* __restrict__ Cb,
                                                   unsigned long long* __restrict__ cand,
                                                   float* __restrict__ out) {
    __shared__ float ssc[128];
    __shared__ int sel[32];
    int t = threadIdx.x;
    int wave = t >> 6, lane = t & 63;
    int bid = blockIdx.x;

    if (bid < NCH * BB) {
        // ================= scoring producer: 128 f-rows of one b =================
        int b = bid >> 5, chunk = bid & 31;
        const f4* qv = (const f4*)(q + b * EE);
        f4 qa = qv[lane];
        f4 qb = qv[64 + lane];
        for (int it = 0; it < 4; ++it) {
            int f0 = chunk * 128 + wave * 32 + it * 8;
            float d[8];
            #pragma unroll
            for (int i = 0; i < 8; ++i) {
                const f4* fv = (const f4*)(fact + ((long)b * FF + f0 + i) * EE);
                f4 fa = fv[lane];
                f4 fb = fv[64 + lane];
                f4 p = qa * fa + qb * fb;
                d[i] = p.x + p.y + p.z + p.w;
            }
            bool h32 = lane & 32;
            float e0, e1, e2, e3;
            {
                float s0 = __shfl_xor(d[0], 32), s1 = __shfl_xor(d[1], 32);
                float s2 = __shfl_xor(d[2], 32), s3 = __shfl_xor(d[3], 32);
                float s4 = __shfl_xor(d[4], 32), s5 = __shfl_xor(d[5], 32);
                float s6 = __shfl_xor(d[6], 32), s7 = __shfl_xor(d[7], 32);
                e0 = h32 ? d[4] + s4 : d[0] + s0;
                e1 = h32 ? d[5] + s5 : d[1] + s1;
                e2 = h32 ? d[6] + s6 : d[2] + s2;
                e3 = h32 ? d[7] + s7 : d[3] + s3;
            }
            bool h16 = lane & 16;
            float g0, g1;
            {
                float s0 = __shfl_xor(e0, 16), s1 = __shfl_xor(e1, 16);
                float s2 = __shfl_xor(e2, 16), s3 = __shfl_xor(e3, 16);
                g0 = h16 ? e2 + s2 : e0 + s0;
                g1 = h16 ? e3 + s3 : e1 + s1;
            }
            bool h8 = lane & 8;
            float hs;
            {
                float s0 = __shfl_xor(g0, 8), s1 = __shfl_xor(g1, 8);
                hs = h8 ? g1 + s1 : g0 + s0;
            }
            hs += __shfl_xor(hs, 4);
            hs += __shfl_xor(hs, 2);
            hs += __shfl_xor(hs, 1);
            if ((lane & 7) == 0) ssc[wave * 32 + it * 8 + ((lane >> 3) & 7)] = hs;
        }
        __syncthreads();

        if (wave == 0) {
            unsigned long long k0 = packkey(ssc[lane], chunk * 128 + lane);
            unsigned long long k1 = packkey(ssc[64 + lane], chunk * 128 + 64 + lane);
            unsigned long long mykey = 0;
            for (int it = 0; it < KK; ++it) {
                unsigned long long best = k0 > k1 ? k0 : k1;
                #pragma unroll
                for (int off = 32; off > 0; off >>= 1) {
                    unsigned long long o = __shfl_xor(best, off, 64);
                    if (o > best) best = o;
                }
                if (lane == it) mykey = best;
                if (k0 == best) k0 = 0;
                if (k1 == best) k1 = 0;
            }
            if (lane < KK)
                __hip_atomic_store(&cand[(size_t)b * (NCH * KK) + chunk * KK + lane], mykey,
                                   __ATOMIC_RELAXED, __HIP_MEMORY_SCOPE_AGENT);
        }
        return;
    }

    // ================= fused tail: (b, mat) =================
    int tb = bid - NCH * BB;
    int b = tb >> 1, mat = tb & 1;

    if (wave == 0) {
        // spin on the 640 candidate slots (data IS the flag; no fences)
        unsigned long long kk[10];
        #pragma unroll
        for (int i = 0; i < 10; ++i) {
            unsigned long long v;
            while ((v = __hip_atomic_load(&cand[(size_t)b * (NCH * KK) + i * 64 + lane],
                                          __ATOMIC_RELAXED, __HIP_MEMORY_SCOPE_AGENT)) == 0ull)
                __builtin_amdgcn_s_sleep(8);
            kk[i] = v;
        }
        for (int it = 0; it < KK; ++it) {
            unsigned long long best = kk[0];
            #pragma unroll
            for (int i = 1; i < 10; ++i) best = kk[i] > best ? kk[i] : best;
            #pragma unroll
            for (int off = 32; off > 0; off >>= 1) {
                unsigned long long o = __shfl_xor(best, off, 64);
                if (o > best) best = o;
            }
            if (lane == 0) sel[it] = FF - 1 - (int)(best & 0xFFFFFFFFu);
            #pragma unroll
            for (int i = 0; i < 10; ++i)
                if (kk[i] == best) kk[i] = 0;
        }
        if (lane == 0) {
            for (int i = KK; i < 32; ++i) sel[i] = sel[0];   // safe dummy rows for M-tile 2
        }
    }
    __syncthreads();

    const float* factb = fact + (long)b * FF * EE;

    // ---- update (f32, bit-identical to r5): mat0 -> h (waves 0,1); mat1 -> c (waves 2,3) ----
    if ((mat == 0) ? (wave < 2) : (wave >= 2)) {
        const float* u = (wave < 2 ? hin : cin) + ((size_t)(wave & 1) * BB + b) * EE;
        const float4* uv = (const float4*)u;
        float4 ua = uv[lane], ub = uv[64 + lane];
        float sk[KK];
        #pragma unroll
        for (int k = 0; k < KK; ++k) {
            const float4* tv = (const float4*)(factb + (long)sel[k] * EE);
            float4 ta = tv[lane], tb2 = tv[64 + lane];
            float d = ua.x * ta.x + ua.y * ta.y + ua.z * ta.z + ua.w * ta.w
                    + ub.x * tb2.x + ub.y * tb2.y + ub.z * tb2.z + ub.w * tb2.w;
            #pragma unroll
            for (int off = 32; off > 0; off >>= 1) d += __shfl_xor(d, off, 64);
            sk[k] = d;
        }
        float m = sk[0];
        #pragma unroll
        for (int k = 1; k < KK; ++k) m = fmaxf(m, sk[k]);
        float sum = 0.f;
        #pragma unroll
        for (int k = 0; k < KK; ++k) { sk[k] = __expf(sk[k] - m); sum += sk[k]; }
        float inv = 1.f / sum;
        float4 oa = {0, 0, 0, 0}, ob = {0, 0, 0, 0};
        #pragma unroll
        for (int k = 0; k < KK; ++k) {
            float p = sk[k] * inv;
            const float4* tv = (const float4*)(factb + (long)sel[k] * EE);
            float4 ta = tv[lane], tb2 = tv[64 + lane];
            oa.x += p * ta.x; oa.y += p * ta.y; oa.z += p * ta.z; oa.w += p * ta.w;
            ob.x += p * tb2.x; ob.y += p * tb2.y; ob.z += p * tb2.z; ob.w += p * tb2.w;
        }
        oa.x += ua.x; oa.y += ua.y; oa.z += ua.z; oa.w += ua.w;
        ob.x += ub.x; ob.y += ub.y; ob.z += ub.z; ob.w += ub.w;
        float* obase = out + (size_t)(wave < 2 ? 0 : NLAYER * BB * HH)
                           + ((size_t)(wave & 1) * BB + b) * HH;
        float4* ov = (float4*)obase;
        ov[lane] = oa;
        ov[64 + lane] = ob;
    }

    // ---- MFMA for this block's mat; wave owns 128 h-cols; A built in-register from f32 fact ----
    {
        const unsigned short* W = Wbf + (size_t)mat * HH * EE;
        const float* bias = mat ? Cb : Ab;
        float* O = out + (size_t)2 * NLAYER * BB * HH
                       + (size_t)mat * BB * KK * HH + (size_t)b * KK * HH;
        int lrow = lane & 15, lk = lane >> 4;
        const float* arow0 = factb + (long)sel[lrow] * EE + lk * 8;
        const float* arow1 = factb + (long)sel[16 + lrow] * EE + lk * 8;

        f32x4 acc[2][8];
        #pragma unroll
        for (int m = 0; m < 2; ++m)
            #pragma unroll
            for (int n = 0; n < 8; ++n) acc[m][n] = (f32x4){0, 0, 0, 0};

        const unsigned short* wbase = W + (size_t)(wave * 128 + lrow) * EE + lk * 8;

        #pragma unroll 2
        for (int ks = 0; ks < 16; ++ks) {
            f4 v0a = *(const f4*)(arow0 + ks * 32);
            f4 v0b = *(const f4*)(arow0 + ks * 32 + 4);
            bf16x8 a0 = cvt8(v0a, v0b);
            f4 v1a = *(const f4*)(arow1 + ks * 32);
            f4 v1b = *(const f4*)(arow1 + ks * 32 + 4);
            bf16x8 a1 = cvt8(v1a, v1b);
            #pragma unroll
            for (int n = 0; n < 8; ++n) {
                bf16x8 bfrag = *(const bf16x8*)(wbase + (size_t)n * 16 * EE + ks * 32);
                acc[0][n] = __builtin_amdgcn_mfma_f32_16x16x32_bf16(a0, bfrag, acc[0][n], 0, 0, 0);
                acc[1][n] = __builtin_amdgcn_mfma_f32_16x16x32_bf16(a1, bfrag, acc[1][n], 0, 0, 0);
            }
        }

        #pragma unroll
        for (int n = 0; n < 8; ++n) {
            int h = wave * 128 + n * 16 + lrow;
            float bv = bias[h];
            #pragma unroll
            for (int r = 0; r < 4; ++r) {
                int k0 = lk * 4 + r;
                O[(size_t)k0 * HH + h] = acc[0][n][r] + bv;
                int k1 = 16 + lk * 4 + r;
                if (k1 < KK) O[(size_t)k1 * HH + h] = acc[1][n][r] + bv;
            }
        }
    }
}

extern "C" void kernel_launch(void* const* d_in, const int* in_sizes, int n_in,
                              void* d_out, int out_size, void* d_ws, size_t ws_size,
                              hipStream_t stream) {
    const int* tok = (const int*)d_in[0];
    const float* fact = (const float*)d_in[1];
    const float* hin = (const float*)d_in[2];
    const float* cin = (const float*)d_in[3];
    const float* emb = (const float*)d_in[4];
    const float* Aw = (const float*)d_in[5];
    const float* Ab = (const float*)d_in[6];
    const float* Cw = (const float*)d_in[7];
    const float* Cb = (const float*)d_in[8];
    float* out = (float*)d_out;

    float* ws = (float*)d_ws;
    float* q = ws;                                                     // 65536 f
    unsigned long long* cand = (unsigned long long*)(ws + 65536);      // 128*640 u64 = 163840 f
    unsigned short* Wbf = (unsigned short*)(ws + 65536 + 163840);      // 524288 us = 262144 f

    prep_kernel<<<784, 256, 0, stream>>>(tok, emb, q, Aw, Cw, Wbf, cand);
    mega_kernel<<<NCH * BB + 256, 256, 0, stream>>>(q, fact, hin, cin, Wbf, Ab, Cb, cand, out);
}

// Round 14
// 212.922 us; speedup vs baseline: 1.1218x; 1.1218x over previous
//
#include <hip/hip_runtime.h>
#include <float.h>
#include <math.h>

#define LL 32
#define BB 128
#define FF 4096
#define EE 512
#define HH 512
#define NLAYER 2
#define KK 20
#define NCH 32

typedef float f4 __attribute__((ext_vector_type(4)));
typedef short bf16x8 __attribute__((ext_vector_type(8)));
typedef float f32x4 __attribute__((ext_vector_type(4)));

__device__ inline unsigned short bf16rne(float x) {
    unsigned u = __float_as_uint(x);
    u += 0x7fff + ((u >> 16) & 1);
    return (unsigned short)(u >> 16);
}

// key==0 unreachable: requires raw float bits 0xFFFFFFFF (negative NaN), never produced.
__device__ inline unsigned long long packkey(float v, int fidx) {
    unsigned u = __float_as_uint(v);
    u ^= ((int)u >> 31) | 0x80000000u;
    return ((unsigned long long)u << 32) | (unsigned)(FF - 1 - fidx);
}

__device__ inline bf16x8 cvt8(f4 a, f4 b) {
    bf16x8 r;
    r[0] = (short)bf16rne(a.x); r[1] = (short)bf16rne(a.y);
    r[2] = (short)bf16rne(a.z); r[3] = (short)bf16rne(a.w);
    r[4] = (short)bf16rne(b.x); r[5] = (short)bf16rne(b.y);
    r[6] = (short)bf16rne(b.z); r[7] = (short)bf16rne(b.w);
    return r;
}

// ---------------- K1: q (0..255) + W->bf16 (256..767) + cand zero (768..783) ----------------
__global__ __launch_bounds__(256) void prep_kernel(const int* __restrict__ tok,
                                                   const float* __restrict__ emb,
                                                   float* __restrict__ q,
                                                   const float* __restrict__ Aw,
                                                   const float* __restrict__ Cw,
                                                   unsigned short* __restrict__ Wbf,
                                                   unsigned long long* __restrict__ cand) {
    int bid = blockIdx.x;
    if (bid < 256) {
        int b = bid >> 1, eh = bid & 1;
        __shared__ int ts[LL];
        if (threadIdx.x < LL) ts[threadIdx.x] = tok[threadIdx.x * BB + b];
        __syncthreads();
        int e = eh * 256 + threadIdx.x;
        float acc = 0.f;
        #pragma unroll
        for (int l = 0; l < LL; ++l) acc += emb[(long)ts[l] * EE + e];
        q[b * EE + e] = acc * (1.0f / LL);
    } else if (bid < 768) {
        int cid = bid - 256;
        int matY = cid >> 8;
        int blkX = cid & 255;
        const float* W = matY ? Cw : Aw;
        unsigned short* dst = Wbf + (size_t)matY * HH * EE;
        int i = (blkX * 256 + threadIdx.x) * 4;
        float4 v = *(const float4*)(W + i);
        ushort4 o;
        o.x = bf16rne(v.x); o.y = bf16rne(v.y); o.z = bf16rne(v.z); o.w = bf16rne(v.w);
        *(ushort4*)(dst + i) = o;
    } else {
        int idx = (bid - 768) * 256 + threadIdx.x;      // 0..4095
        unsigned long long* p = cand + (size_t)idx * KK;
        #pragma unroll
        for (int i = 0; i < KK; ++i) p[i] = 0ull;
    }
}

// ---------------- K2: mega — scoring producers (0..4095) + fused tails (4096..4351) ----------------
__global__ __launch_bounds__(256) void mega_kernel(const float* __restrict__ q,
                                                   const float* __restrict__ fact,
                                                   const float* __restrict__ hin,
                                                   const float* __restrict__ cin,
                                                   const unsigned short* __restrict__ Wbf,
                                                   const float* __restrict__ Ab,
                                                   const float* __restrict__ Cb,
                                                   unsigned long long* __restrict__ cand,
                                                   float* __restrict__ out) {
    __shared__ float ssc[128];
    __shared__ int sel[32];
    int t = threadIdx.x;
    int wave = t >> 6, lane = t & 63;
    int bid = blockIdx.x;

    if (bid < NCH * BB) {
        // ================= scoring producer: 128 f-rows of one b =================
        int b = bid >> 5, chunk = bid & 31;
        const f4* qv = (const f4*)(q + b * EE);
        f4 qa = qv[lane];
        f4 qb = qv[64 + lane];
        for (int it = 0; it < 4; ++it) {
            int f0 = chunk * 128 + wave * 32 + it * 8;
            float d[8];
            #pragma unroll
            for (int i = 0; i < 8; ++i) {
                const f4* fv = (const f4*)(fact + ((long)b * FF + f0 + i) * EE);
                f4 fa = __builtin_nontemporal_load(fv + lane);
                f4 fb = __builtin_nontemporal_load(fv + 64 + lane);
                f4 p = qa * fa + qb * fb;
                d[i] = p.x + p.y + p.z + p.w;
            }
            bool h32 = lane & 32;
            float e0, e1, e2, e3;
            {
                float s0 = __shfl_xor(d[0], 32), s1 = __shfl_xor(d[1], 32);
                float s2 = __shfl_xor(d[2], 32), s3 = __shfl_xor(d[3], 32);
                float s4 = __shfl_xor(d[4], 32), s5 = __shfl_xor(d[5], 32);
                float s6 = __shfl_xor(d[6], 32), s7 = __shfl_xor(d[7], 32);
                e0 = h32 ? d[4] + s4 : d[0] + s0;
                e1 = h32 ? d[5] + s5 : d[1] + s1;
                e2 = h32 ? d[6] + s6 : d[2] + s2;
                e3 = h32 ? d[7] + s7 : d[3] + s3;
            }
            bool h16 = lane & 16;
            float g0, g1;
            {
                float s0 = __shfl_xor(e0, 16), s1 = __shfl_xor(e1, 16);
                float s2 = __shfl_xor(e2, 16), s3 = __shfl_xor(e3, 16);
                g0 = h16 ? e2 + s2 : e0 + s0;
                g1 = h16 ? e3 + s3 : e1 + s1;
            }
            bool h8 = lane & 8;
            float hs;
            {
                float s0 = __shfl_xor(g0, 8), s1 = __shfl_xor(g1, 8);
                hs = h8 ? g1 + s1 : g0 + s0;
            }
            hs += __shfl_xor(hs, 4);
            hs += __shfl_xor(hs, 2);
            hs += __shfl_xor(hs, 1);
            if ((lane & 7) == 0) ssc[wave * 32 + it * 8 + ((lane >> 3) & 7)] = hs;
        }
        __syncthreads();

        if (wave == 0) {
            unsigned long long k0 = packkey(ssc[lane], chunk * 128 + lane);
            unsigned long long k1 = packkey(ssc[64 + lane], chunk * 128 + 64 + lane);
            unsigned long long mykey = 0;
            for (int it = 0; it < KK; ++it) {
                unsigned long long best = k0 > k1 ? k0 : k1;
                #pragma unroll
                for (int off = 32; off > 0; off >>= 1) {
                    unsigned long long o = __shfl_xor(best, off, 64);
                    if (o > best) best = o;
                }
                if (lane == it) mykey = best;
                if (k0 == best) k0 = 0;
                if (k1 == best) k1 = 0;
            }
            if (lane < KK)
                __hip_atomic_store(&cand[(size_t)b * (NCH * KK) + chunk * KK + lane], mykey,
                                   __ATOMIC_RELAXED, __HIP_MEMORY_SCOPE_AGENT);
        }
        return;
    }

    // ================= fused tail: (b, mat) =================
    int tb = bid - NCH * BB;
    int b = tb >> 1, mat = tb & 1;

    if (wave == 0) {
        // spin on the 640 candidate slots (data IS the flag; no fences)
        unsigned long long kk[10];
        #pragma unroll
        for (int i = 0; i < 10; ++i) {
            unsigned long long v;
            while ((v = __hip_atomic_load(&cand[(size_t)b * (NCH * KK) + i * 64 + lane],
                                          __ATOMIC_RELAXED, __HIP_MEMORY_SCOPE_AGENT)) == 0ull)
                __builtin_amdgcn_s_sleep(8);
            kk[i] = v;
        }
        for (int it = 0; it < KK; ++it) {
            unsigned long long best = kk[0];
            #pragma unroll
            for (int i = 1; i < 10; ++i) best = kk[i] > best ? kk[i] : best;
            #pragma unroll
            for (int off = 32; off > 0; off >>= 1) {
                unsigned long long o = __shfl_xor(best, off, 64);
                if (o > best) best = o;
            }
            if (lane == 0) sel[it] = FF - 1 - (int)(best & 0xFFFFFFFFu);
            #pragma unroll
            for (int i = 0; i < 10; ++i)
                if (kk[i] == best) kk[i] = 0;
        }
        if (lane == 0) {
            for (int i = KK; i < 32; ++i) sel[i] = sel[0];   // safe dummy rows for M-tile 2
        }
    }
    __syncthreads();

    const float* factb = fact + (long)b * FF * EE;

    // ---- update (f32, bit-identical to r5): mat0 -> h (waves 0,1); mat1 -> c (waves 2,3) ----
    if ((mat == 0) ? (wave < 2) : (wave >= 2)) {
        const float* u = (wave < 2 ? hin : cin) + ((size_t)(wave & 1) * BB + b) * EE;
        const float4* uv = (const float4*)u;
        float4 ua = uv[lane], ub = uv[64 + lane];
        float sk[KK];
        #pragma unroll
        for (int k = 0; k < KK; ++k) {
            const float4* tv = (const float4*)(factb + (long)sel[k] * EE);
            float4 ta = tv[lane], tb2 = tv[64 + lane];
            float d = ua.x * ta.x + ua.y * ta.y + ua.z * ta.z + ua.w * ta.w
                    + ub.x * tb2.x + ub.y * tb2.y + ub.z * tb2.z + ub.w * tb2.w;
            #pragma unroll
            for (int off = 32; off > 0; off >>= 1) d += __shfl_xor(d, off, 64);
            sk[k] = d;
        }
        float m = sk[0];
        #pragma unroll
        for (int k = 1; k < KK; ++k) m = fmaxf(m, sk[k]);
        float sum = 0.f;
        #pragma unroll
        for (int k = 0; k < KK; ++k) { sk[k] = __expf(sk[k] - m); sum += sk[k]; }
        float inv = 1.f / sum;
        float4 oa = {0, 0, 0, 0}, ob = {0, 0, 0, 0};
        #pragma unroll
        for (int k = 0; k < KK; ++k) {
            float p = sk[k] * inv;
            const float4* tv = (const float4*)(factb + (long)sel[k] * EE);
            float4 ta = tv[lane], tb2 = tv[64 + lane];
            oa.x += p * ta.x; oa.y += p * ta.y; oa.z += p * ta.z; oa.w += p * ta.w;
            ob.x += p * tb2.x; ob.y += p * tb2.y; ob.z += p * tb2.z; ob.w += p * tb2.w;
        }
        oa.x += ua.x; oa.y += ua.y; oa.z += ua.z; oa.w += ua.w;
        ob.x += ub.x; ob.y += ub.y; ob.z += ub.z; ob.w += ub.w;
        float* obase = out + (size_t)(wave < 2 ? 0 : NLAYER * BB * HH)
                           + ((size_t)(wave & 1) * BB + b) * HH;
        float4* ov = (float4*)obase;
        ov[lane] = oa;
        ov[64 + lane] = ob;
    }

    // ---- MFMA for this block's mat; wave owns 128 h-cols; A built in-register from f32 fact ----
    {
        const unsigned short* W = Wbf + (size_t)mat * HH * EE;
        const float* bias = mat ? Cb : Ab;
        float* O = out + (size_t)2 * NLAYER * BB * HH
                       + (size_t)mat * BB * KK * HH + (size_t)b * KK * HH;
        int lrow = lane & 15, lk = lane >> 4;
        const float* arow0 = factb + (long)sel[lrow] * EE + lk * 8;
        const float* arow1 = factb + (long)sel[16 + lrow] * EE + lk * 8;

        f32x4 acc[2][8];
        #pragma unroll
        for (int m = 0; m < 2; ++m)
            #pragma unroll
            for (int n = 0; n < 8; ++n) acc[m][n] = (f32x4){0, 0, 0, 0};

        const unsigned short* wbase = W + (size_t)(wave * 128 + lrow) * EE + lk * 8;

        #pragma unroll 2
        for (int ks = 0; ks < 16; ++ks) {
            f4 v0a = *(const f4*)(arow0 + ks * 32);
            f4 v0b = *(const f4*)(arow0 + ks * 32 + 4);
            bf16x8 a0 = cvt8(v0a, v0b);
            f4 v1a = *(const f4*)(arow1 + ks * 32);
            f4 v1b = *(const f4*)(arow1 + ks * 32 + 4);
            bf16x8 a1 = cvt8(v1a, v1b);
            #pragma unroll
            for (int n = 0; n < 8; ++n) {
                bf16x8 bfrag = *(const bf16x8*)(wbase + (size_t)n * 16 * EE + ks * 32);
                acc[0][n] = __builtin_amdgcn_mfma_f32_16x16x32_bf16(a0, bfrag, acc[0][n], 0, 0, 0);
                acc[1][n] = __builtin_amdgcn_mfma_f32_16x16x32_bf16(a1, bfrag, acc[1][n], 0, 0, 0);
            }
        }

        #pragma unroll
        for (int n = 0; n < 8; ++n) {
            int h = wave * 128 + n * 16 + lrow;
            float bv = bias[h];
            #pragma unroll
            for (int r = 0; r < 4; ++r) {
                int k0 = lk * 4 + r;
                O[(size_t)k0 * HH + h] = acc[0][n][r] + bv;
                int k1 = 16 + lk * 4 + r;
                if (k1 < KK) O[(size_t)k1 * HH + h] = acc[1][n][r] + bv;
            }
        }
    }
}

extern "C" void kernel_launch(void* const* d_in, const int* in_sizes, int n_in,
                              void* d_out, int out_size, void* d_ws, size_t ws_size,
                              hipStream_t stream) {
    const int* tok = (const int*)d_in[0];
    const float* fact = (const float*)d_in[1];
    const float* hin = (const float*)d_in[2];
    const float* cin = (const float*)d_in[3];
    const float* emb = (const float*)d_in[4];
    const float* Aw = (const float*)d_in[5];
    const float* Ab = (const float*)d_in[6];
    const float* Cw = (const float*)d_in[7];
    const float* Cb = (const float*)d_in[8];
    float* out = (float*)d_out;

    float* ws = (float*)d_ws;
    float* q = ws;                                                     // 65536 f
    unsigned long long* cand = (unsigned long long*)(ws + 65536);      // 128*640 u64 = 163840 f
    unsigned short* Wbf = (unsigned short*)(ws + 65536 + 163840);      // 524288 us = 262144 f

    prep_kernel<<<784, 256, 0, stream>>>(tok, emb, q, Aw, Cw, Wbf, cand);
    mega_kernel<<<NCH * BB + 256, 256, 0, stream>>>(q, fact, hin, cin, Wbf, Ab, Cb, cand, out);
}